// Round 8
// baseline (622.961 us; speedup 1.0000x reference)
//
#include <hip/hip_runtime.h>

// Problem constants (fixed by the reference).
#define Bn    16384
#define Tn    2048
#define HIDn  5
#define NBINS 2048

typedef float v2f __attribute__((ext_vector_type(2)));

static __device__ __forceinline__ float rcp_fast(float v) {
    return __builtin_amdgcn_rcpf(v);
}
static __device__ __forceinline__ float med3(float x, float lo, float hi) {
    return __builtin_amdgcn_fmed3f(x, lo, hi);   // 1-op clamp
}

// Quad broadcast via DPP (quad_perm) — full-rate VALU, ~4-8 cy dependent
// latency (vs ~120 cy for ds_swizzle). All lanes always active (cndmask
// commit, no exec-divergence), so bound_ctrl semantics are safe.
template <int SRC>
static __device__ __forceinline__ float qbcast(float v) {
    constexpr int ctrl = SRC | (SRC << 2) | (SRC << 4) | (SRC << 6);
    return __int_as_float(
        __builtin_amdgcn_update_dpp(0, __float_as_int(v), ctrl, 0xF, 0xF, true));
}

// ---------------------------------------------------------------------------
// Pass 0: zero the global histogram bins (ws is poisoned 0xAA).
// ---------------------------------------------------------------------------
__global__ void zero_kernel(int* __restrict__ gbins) {
    gbins[blockIdx.x * 256 + threadIdx.x] = 0;
}

// ---------------------------------------------------------------------------
// Pass 1: lengths[b] = count of nonzero x[b,t] + histogram of d = NBINS-len.
// One wave per row, coalesced float4.
// ---------------------------------------------------------------------------
__global__ __launch_bounds__(256) void len_kernel(const float* __restrict__ x,
                                                  int* __restrict__ lengths,
                                                  int* __restrict__ gbins) {
    const int gtid = blockIdx.x * 256 + threadIdx.x;
    const int row  = gtid >> 6;
    const int lane = threadIdx.x & 63;
    const float4* r = reinterpret_cast<const float4*>(x + (size_t)row * Tn);
    int cnt = 0;
    #pragma unroll
    for (int i = 0; i < Tn / 4 / 64; ++i) {
        float4 v = r[i * 64 + lane];
        cnt += (v.x != 0.0f) + (v.y != 0.0f) + (v.z != 0.0f) + (v.w != 0.0f);
    }
    #pragma unroll
    for (int off = 32; off > 0; off >>= 1) cnt += __shfl_xor(cnt, off, 64);
    if (lane == 0) {
        lengths[row] = cnt;
        const int d = max(0, min(NBINS - 1, NBINS - cnt));
        atomicAdd(&gbins[d], 1);
    }
}

// ---------------------------------------------------------------------------
// Pass 1.5: scan histogram + scatter -> perm[] sorted by length DESC.
// ---------------------------------------------------------------------------
__global__ __launch_bounds__(1024) void sort_kernel(const int* __restrict__ lengths,
                                                    const int* __restrict__ gbins,
                                                    int* __restrict__ perm) {
    __shared__ int bins[NBINS];
    __shared__ int bsum[1024];
    const int tid = threadIdx.x;
    bins[tid]        = gbins[tid];
    bins[tid + 1024] = gbins[tid + 1024];
    __syncthreads();
    const int a0 = bins[2 * tid], a1 = bins[2 * tid + 1];
    const int s = a0 + a1;
    bsum[tid] = s;
    __syncthreads();
    int acc = s;
    for (int off = 1; off < 1024; off <<= 1) {
        int v = (tid >= off) ? bsum[tid - off] : 0;
        __syncthreads();
        acc += v;
        bsum[tid] = acc;
        __syncthreads();
    }
    const int excl = acc - s;
    bins[2 * tid]     = excl;
    bins[2 * tid + 1] = excl + a0;
    __syncthreads();
    for (int i = tid; i < Bn; i += 1024) {
        int d = NBINS - lengths[i];
        d = max(0, min(NBINS - 1, d));
        const int p = atomicAdd(&bins[d], 1);
        perm[p] = i;
    }
}

// ---------------------------------------------------------------------------
// Pass 2: LSTM. 4 lanes per sequence (quad), DPP comms (R5-R7 showed the wall
// is serial-chain latency; ds_swizzle's ~120-cy LDS round trip per step was
// the floor). Lane q owns hidden index q: gates i_q,f_q,g_q,o_q + the slot-4
// gate of TYPE q (row 5q+4). c_q is lane-local; c_4 replicated via 4 DPP.
// All activations Pade(7,6) tanh (clamp +-4; sigma = 0.5+0.5*tanh(x/2), 0.5
// folded into weights) — zero exp; 4 rcp/step. cndmask state-commit, no
// exec branches. Sorted static 1:1 assignment keeps wave lengths uniform.
// 65536 threads = 1024 waves = 1 wave/SIMD.
// ---------------------------------------------------------------------------
__global__ __launch_bounds__(256) void lstm_kernel(const float* __restrict__ x,
                                                   const float* __restrict__ Wih,
                                                   const float* __restrict__ Whh,
                                                   const float* __restrict__ bih,
                                                   const float* __restrict__ bhh,
                                                   const int* __restrict__ lengths,
                                                   const int* __restrict__ perm,
                                                   float* __restrict__ out) {
    const int gtid = blockIdx.x * 256 + threadIdx.x;
    const int grp  = gtid >> 2;              // quad index = sorted rank
    const int q    = gtid & 3;               // owned hidden index / slot-4 type

    const int b   = perm[grp];
    const int len = lengths[b];

    // Pairs A=(i_q,f_q) scale 0.5, B=(g_q,o_q) scale (1,0.5); slot-4 gate row
    // 5q+4 with type-q scale.
    v2f wihA, wihB, bsA, bsB, whhA[HIDn], whhB[HIDn];
    float wih4, bs4, whh4[HIDn];
    {
        const int gi = q, gf = 5 + q, gg = 10 + q, go = 15 + q, g4 = 5 * q + 4;
        const float s4 = (q == 2) ? 1.0f : 0.5f;
        wihA = (v2f){ Wih[gi] * 0.5f, Wih[gf] * 0.5f };
        wihB = (v2f){ Wih[gg],        Wih[go] * 0.5f };
        wih4 = Wih[g4] * s4;
        bsA  = (v2f){ (bih[gi] + bhh[gi]) * 0.5f, (bih[gf] + bhh[gf]) * 0.5f };
        bsB  = (v2f){ (bih[gg] + bhh[gg]),        (bih[go] + bhh[go]) * 0.5f };
        bs4  = (bih[g4] + bhh[g4]) * s4;
        #pragma unroll
        for (int kk = 0; kk < HIDn; ++kk) {
            whhA[kk] = (v2f){ Whh[gi * HIDn + kk] * 0.5f, Whh[gf * HIDn + kk] * 0.5f };
            whhB[kk] = (v2f){ Whh[gg * HIDn + kk],        Whh[go * HIDn + kk] * 0.5f };
            whh4[kk] = Whh[g4 * HIDn + kk] * s4;
        }
    }
    // slot-4 activation affine: sigma types -> 0.5t+0.5; g type raw.
    const float m4 = (q == 2) ? 1.0f : 0.5f;
    const float a4b = (q == 2) ? 0.0f : 0.5f;

    const float* xrow = x + (size_t)b * Tn;
    float h0 = 0, h1 = 0, h2 = 0, h3 = 0, h4 = 0;   // gathered h (all lanes)
    float hq = 0, cq = 0, c4 = 0;                   // lane-local state

    float4 xA = *reinterpret_cast<const float4*>(xrow);
    float4 xB = *reinterpret_cast<const float4*>(xrow + 4);
    for (int t = 0; __any(t < len); t += 8) {
        // Prefetch the next 8 steps' x before the compute body.
        const float4 nA = *reinterpret_cast<const float4*>(xrow + min(t + 8,  Tn - 8));
        const float4 nB = *reinterpret_cast<const float4*>(xrow + min(t + 12, Tn - 4));
        const float xs[8] = { xA.x, xA.y, xA.z, xA.w, xB.x, xB.y, xB.z, xB.w };

        #pragma unroll
        for (int s = 0; s < 8; ++s) {
            const float xv = xs[s];
            // x-terms (independent of h).
            v2f   pA = xv * wihA + bsA;
            v2f   pB = xv * wihB + bsB;
            float p4 = fmaf(xv, wih4, bs4);
            // Tree dots: (h0,h1,h2) chain + (h3,h4) chain, join.
            v2f uA = h0 * whhA[0] + pA;
            v2f uB = h0 * whhB[0] + pB;
            uA = h1 * whhA[1] + uA;   uB = h1 * whhB[1] + uB;
            uA = h2 * whhA[2] + uA;   uB = h2 * whhB[2] + uB;
            v2f vA = h4 * whhA[4] + h3 * whhA[3];
            v2f vB = h4 * whhB[4] + h3 * whhB[3];
            pA = uA + vA;  pB = uB + vB;
            {
                float u4 = fmaf(h0, whh4[0], p4);
                u4 = fmaf(h1, whh4[1], u4);
                u4 = fmaf(h2, whh4[2], u4);
                float v4 = fmaf(h4, whh4[4], h3 * whh4[3]);
                p4 = u4 + v4;
            }
            // Pade(7,6) tanh on all five pre-acts (clamp +-4).
            v2f tA, tB;
            tA.x = med3(pA.x, -4.0f, 4.0f);  tA.y = med3(pA.y, -4.0f, 4.0f);
            tB.x = med3(pB.x, -4.0f, 4.0f);  tB.y = med3(pB.y, -4.0f, 4.0f);
            const float t4c = med3(p4, -4.0f, 4.0f);
            const v2f zA = tA * tA, zB = tB * tB;
            const float z4 = t4c * t4c;
            const v2f nAp = (zA * 21.0f + 1260.0f) * zA + 10395.0f;
            const v2f nBp = (zB * 21.0f + 1260.0f) * zB + 10395.0f;
            const float n4 = fmaf(z4, fmaf(z4, 21.0f, 1260.0f), 10395.0f);
            const v2f dA = ((zA + 210.0f) * zA + 4725.0f) * zA + 10395.0f;
            const v2f dB = ((zB + 210.0f) * zB + 4725.0f) * zB + 10395.0f;
            const float d4 = fmaf(z4, fmaf(z4, z4 + 210.0f, 4725.0f), 10395.0f);
            const float rA = rcp_fast(dA.x * dA.y);
            const float rB = rcp_fast(dB.x * dB.y);
            const float r4 = rcp_fast(d4);
            const v2f pnA = tA * nAp, pnB = tB * nBp;
            const float ti = pnA.x * (dA.y * rA);
            const float tf = pnA.y * (dA.x * rA);
            const float tg = pnB.x * (dB.y * rB);
            const float to = pnB.y * (dB.x * rB);
            const float t4v = (t4c * n4) * r4;
            const float gi_ = fmaf(ti, 0.5f, 0.5f);   // sigmoid(i_q)
            const float gf_ = fmaf(tf, 0.5f, 0.5f);   // sigmoid(f_q)
            const float go_ = fmaf(to, 0.5f, 0.5f);   // sigmoid(o_q)
            const float a4  = fmaf(t4v, m4, a4b);     // activated slot-4 gate (type q)

            const float cnq = fmaf(gf_, cq, gi_ * tg);

            // slot-4 gate gather (4 DPP, same register) + c4 update.
            const float i4 = qbcast<0>(a4);
            const float f4 = qbcast<1>(a4);
            const float g4v = qbcast<2>(a4);
            const float o4 = qbcast<3>(a4);
            const float cn4 = fmaf(f4, c4, i4 * g4v);

            // Spine tanh over (c_q, c_4), packed.
            v2f tC;
            tC.x = med3(cnq, -4.0f, 4.0f);
            tC.y = med3(cn4, -4.0f, 4.0f);
            const v2f zC = tC * tC;
            const v2f nC = (zC * 21.0f + 1260.0f) * zC + 10395.0f;
            const v2f dC = ((zC + 210.0f) * zC + 4725.0f) * zC + 10395.0f;
            const float rC = rcp_fast(dC.x * dC.y);
            const v2f pnC = tC * nC;
            const float hnq = (pnC.x * (dC.y * rC)) * go_;
            const float hn4 = (pnC.y * (dC.x * rC)) * o4;

            // Conditional commit — no exec-mask divergence, quads past their
            // length freeze.
            const bool upd = (t + s) < len;
            cq = upd ? cnq : cq;
            c4 = upd ? cn4 : c4;
            hq = upd ? hnq : hq;
            h4 = upd ? hn4 : h4;

            // h all-gather for the next step (DPP).
            h0 = qbcast<0>(hq);
            h1 = qbcast<1>(hq);
            h2 = qbcast<2>(hq);
            h3 = qbcast<3>(hq);
        }
        xA = nA;
        xB = nB;
    }

    out[(size_t)b * HIDn + q] = hq;              // lane q owns h_q
    if (q == 0) out[(size_t)b * HIDn + 4] = h4;  // h_4 replicated; lane 0 writes
}

extern "C" void kernel_launch(void* const* d_in, const int* in_sizes, int n_in,
                              void* d_out, int out_size, void* d_ws, size_t ws_size,
                              hipStream_t stream) {
    const float* x   = (const float*)d_in[0];  // [B,1,T,1]
    const float* Wih = (const float*)d_in[1];  // [20,1]
    const float* Whh = (const float*)d_in[2];  // [20,5]
    const float* bih = (const float*)d_in[3];  // [20]
    const float* bhh = (const float*)d_in[4];  // [20]
    float* out = (float*)d_out;                // [1,B,5]

    int* lengths = (int*)d_ws;                 // [0, Bn)
    int* perm    = lengths + Bn;               // [Bn, 2Bn)
    int* gbins   = perm + Bn;                  // [2Bn, 2Bn+NBINS)

    zero_kernel<<<NBINS / 256, 256, 0, stream>>>(gbins);
    len_kernel<<<Bn / 4, 256, 0, stream>>>(x, lengths, gbins);
    sort_kernel<<<1, 1024, 0, stream>>>(lengths, gbins, perm);
    lstm_kernel<<<Bn * 4 / 256, 256, 0, stream>>>(x, Wih, Whh, bih, bhh,
                                                  lengths, perm, out);
}